// Round 10
// baseline (136.039 us; speedup 1.0000x reference)
//
#include <hip/hip_runtime.h>
#include <hip/hip_bf16.h>

// FFN: out = x + fc2(relu(fc1(LN(x)))), x:(ntok,16) fp32, ntok % 128 == 0.
// R12: TLP probe. R6's kernel VERBATIM (best measured: 43.4us/dispatch,
// 2.4 TB/s), re-cut from 4-wave/256-thread blocks into 2-wave/128-thread
// blocks (BT=128, grid=8192). The kernel is wave-self-contained (no LDS, no
// barriers, per-wave weight fragments), so this is a pure launch-geometry
// A/B: 16 WG-slots/CU x 2 waves = 32 waves/CU possible vs the ~11-12
// observed for every 4-wave variant. Tests whether wave residency is the
// concurrency cap behind the constant 2.3-2.4 TB/s.
// Carried evidence: plain cached stores (R8: nt-stores +40MB WRITE);
// natural VGPR allocation, never force below (R7 spill); residual loads
// kept (R9b: removing them cost +10us); no software pipelining (R10/R11:
// compiler defeats it or holds it at a VGPR/scratch cost).

constexpr int H     = 16;
constexpr int D     = 64;
constexpr int TPI   = 32;              // tokens per wave-iteration (2 n-tiles)
constexpr int NIT   = 2;               // iterations per wave
constexpr int WAVES = 2;               // waves per block
constexpr int BT    = WAVES * TPI * NIT;   // 128 tokens per block

typedef __attribute__((ext_vector_type(8))) short    short8;
typedef __attribute__((ext_vector_type(4))) float    floatx4;
typedef __attribute__((ext_vector_type(4))) unsigned uintx4;

__device__ inline unsigned pk2(float a, float b) { // low = a, high = b
    __hip_bfloat162 h = __float22bfloat162_rn(make_float2(a, b));
    unsigned u; __builtin_memcpy(&u, &h, 4); return u;
}
__device__ inline floatx4 relu4(floatx4 v) {
    v.x = fmaxf(v.x, 0.f); v.y = fmaxf(v.y, 0.f);
    v.z = fmaxf(v.z, 0.f); v.w = fmaxf(v.w, 0.f);
    return v;
}

// fc1 (4 m-tiles) -> relu -> register repack -> fc2 (2 k-tiles), C-in = b2.
__device__ inline floatx4 tile_ffn(const short8* a1, const short8* a2,
                                   floatx4 c2, short8 by) {
    const floatx4 z = {0.f, 0.f, 0.f, 0.f};
    floatx4 h0 = relu4(__builtin_amdgcn_mfma_f32_16x16x32_bf16(a1[0], by, z, 0, 0, 0));
    floatx4 h1 = relu4(__builtin_amdgcn_mfma_f32_16x16x32_bf16(a1[1], by, z, 0, 0, 0));
    floatx4 h2 = relu4(__builtin_amdgcn_mfma_f32_16x16x32_bf16(a1[2], by, z, 0, 0, 0));
    floatx4 h3 = relu4(__builtin_amdgcn_mfma_f32_16x16x32_bf16(a1[3], by, z, 0, 0, 0));
    uintx4 r0 = { pk2(h0.x, h0.y), pk2(h0.z, h0.w), pk2(h1.x, h1.y), pk2(h1.z, h1.w) };
    uintx4 r1 = { pk2(h2.x, h2.y), pk2(h2.z, h2.w), pk2(h3.x, h3.y), pk2(h3.z, h3.w) };
    short8 bh0, bh1;
    __builtin_memcpy(&bh0, &r0, 16);
    __builtin_memcpy(&bh1, &r1, 16);
    floatx4 o = __builtin_amdgcn_mfma_f32_16x16x32_bf16(a2[0], bh0, c2, 0, 0, 0);
    o = __builtin_amdgcn_mfma_f32_16x16x32_bf16(a2[1], bh1, o, 0, 0, 0);
    return o;
}

__global__ __launch_bounds__(128, 5) void ffn_kernel(
    const float* __restrict__ x,
    const float* __restrict__ ln_g,
    const float* __restrict__ ln_b,
    const float* __restrict__ w1,
    const float* __restrict__ b1,
    const float* __restrict__ w2,
    const float* __restrict__ b2,
    float* __restrict__ out,
    int ntok)
{
    const int tid = threadIdx.x;
    const int w = tid >> 6, l = tid & 63;
    const int li = l & 15, q = l >> 4;
    const int hb = q >> 1;           // 0: this lane's LN covers tile-A, 1: tile-B
    const int k0 = (q & 1) * 8;      // feature base this lane covers

    // ---- per-lane weight fragments, direct from global (cache-resident) ----
    // a1[mt]: A-frag of [w1 | b1 | 0] row d=16*mt+li, k = q*8 .. q*8+7
    short8 a1[4];
    #pragma unroll
    for (int mt = 0; mt < 4; mt++) {
        const int d = 16 * mt + li;
        uintx4 u = {0u, 0u, 0u, 0u};
        if (q < 2) {
            floatx4 wa = *(const floatx4*)(w1 + d * H + k0);
            floatx4 wb = *(const floatx4*)(w1 + d * H + k0 + 4);
            u.x = pk2(wa.x, wa.y); u.y = pk2(wa.z, wa.w);
            u.z = pk2(wb.x, wb.y); u.w = pk2(wb.z, wb.w);
        } else if (q == 2) {
            u.x = pk2(b1[d], 0.f);   // k=16 slot carries b1 (B-side supplies 1.0)
        }
        __builtin_memcpy(&a1[mt], &u, 16);
    }
    // a2[kt]: w2 row li, delta-permuted cols = two contiguous float4 spans:
    //   j=0..3 -> col kt*32+4q+j ; j=4..7 -> col kt*32+16+4q+(j-4)
    short8 a2[2];
    #pragma unroll
    for (int kt = 0; kt < 2; kt++) {
        floatx4 wa = *(const floatx4*)(w2 + li * D + kt * 32 + 4 * q);
        floatx4 wb = *(const floatx4*)(w2 + li * D + kt * 32 + 16 + 4 * q);
        uintx4 u = { pk2(wa.x, wa.y), pk2(wa.z, wa.w), pk2(wb.x, wb.y), pk2(wb.z, wb.w) };
        __builtin_memcpy(&a2[kt], &u, 16);
    }
    const floatx4 c2 = *(const floatx4*)(b2 + 4 * q);
    const floatx4 ga = *(const floatx4*)(ln_g + k0);
    const floatx4 gb = *(const floatx4*)(ln_g + k0 + 4);
    const floatx4 ea = *(const floatx4*)(ln_b + k0);
    const floatx4 eb = *(const floatx4*)(ln_b + k0 + 4);

    const int tok0 = blockIdx.x * BT + w * (TPI * NIT);
    // fragment-layout x pointer: own token = base + hb*16 + li, features k0..k0+7
    const float* xfrag = x + (size_t)(tok0 + hb * 16 + li) * H + k0;

    floatx4 xa = *(const floatx4*)(xfrag);
    floatx4 xb = *(const floatx4*)(xfrag + 4);

    #pragma unroll
    for (int it = 0; it < NIT; ++it) {
        // prefetch next iteration's fragment (HBM/L3-critical path)
        floatx4 na = xa, nb = xb;
        if (it + 1 < NIT) {
            const float* nx = xfrag + (size_t)(it + 1) * TPI * H;
            na = *(const floatx4*)(nx);
            nb = *(const floatx4*)(nx + 4);
        }
        const int base = tok0 + it * TPI;
        // residual loads: same lines the fragment loads touched -> L1/L2 hits
        const size_t rA = (size_t)(base + li) * H + 4 * q;
        const floatx4 xrA = *(const floatx4*)(x + rA);
        const floatx4 xrB = *(const floatx4*)(x + rA + 16 * H);

        // ---- LN over this lane's 8 features (partner = lane^16, same token) ----
        float ps = (xa.x + xa.y) + (xa.z + xa.w) + (xb.x + xb.y) + (xb.z + xb.w);
        float pq = 0.f;
        pq = fmaf(xa.x, xa.x, pq); pq = fmaf(xa.y, xa.y, pq);
        pq = fmaf(xa.z, xa.z, pq); pq = fmaf(xa.w, xa.w, pq);
        pq = fmaf(xb.x, xb.x, pq); pq = fmaf(xb.y, xb.y, pq);
        pq = fmaf(xb.z, xb.z, pq); pq = fmaf(xb.w, xb.w, pq);
        ps += __shfl_xor(ps, 16);
        pq += __shfl_xor(pq, 16);
        const float mean = ps * (1.0f / H);
        const float var  = fmaf(-mean, mean, pq * (1.0f / H));
        const float inv  = rsqrtf(var + 1e-5f);
        const float sa = inv, sb = -mean * inv;

        const float y0 = fmaf(fmaf(xa.x, sa, sb), ga.x, ea.x);
        const float y1 = fmaf(fmaf(xa.y, sa, sb), ga.y, ea.y);
        const float y2 = fmaf(fmaf(xa.z, sa, sb), ga.z, ea.z);
        const float y3 = fmaf(fmaf(xa.w, sa, sb), ga.w, ea.w);
        const float y4 = fmaf(fmaf(xb.x, sa, sb), gb.x, eb.x);
        const float y5 = fmaf(fmaf(xb.y, sa, sb), gb.y, eb.y);
        const float y6 = fmaf(fmaf(xb.z, sa, sb), gb.z, eb.z);
        const float y7 = fmaf(fmaf(xb.w, sa, sb), gb.w, eb.w);

        const unsigned p0 = pk2(y0, y1), p1 = pk2(y2, y3),
                       p2 = pk2(y4, y5), p3 = pk2(y6, y7);
        // hand tile-B's y (held by q>=2 lanes) to q<2 lanes, and vice versa
        const unsigned s0 = __shfl_xor(p0, 32), s1 = __shfl_xor(p1, 32),
                       s2 = __shfl_xor(p2, 32), s3 = __shfl_xor(p3, 32);

        const bool lo = (q < 2);
        const unsigned cq2 = (q == 2) ? 0x3F80u : 0u;  // bf16 1.0 at k=16 (b1 fold)
        uintx4 uA = { lo ? p0 : cq2, lo ? p1 : 0u, lo ? p2 : 0u, lo ? p3 : 0u };
        uintx4 uB = { lo ? s0 : cq2, lo ? s1 : 0u, lo ? s2 : 0u, lo ? s3 : 0u };
        short8 byA, byB;
        __builtin_memcpy(&byA, &uA, 16);
        __builtin_memcpy(&byB, &uB, 16);

        // ---- tile A: 16 tokens, residual + coalesced store ----
        floatx4 oA = tile_ffn(a1, a2, c2, byA);
        oA += xrA;
        *(floatx4*)(out + rA) = oA;
        // ---- tile B ----
        floatx4 oB = tile_ffn(a1, a2, c2, byB);
        oB += xrB;
        *(floatx4*)(out + rA + 16 * H) = oB;

        xa = na; xb = nb;
    }
    (void)ntok;
}

extern "C" void kernel_launch(void* const* d_in, const int* in_sizes, int n_in,
                              void* d_out, int out_size, void* d_ws, size_t ws_size,
                              hipStream_t stream) {
    const float* x   = (const float*)d_in[0];
    const float* g   = (const float*)d_in[1];
    const float* be  = (const float*)d_in[2];
    const float* w1  = (const float*)d_in[3];
    const float* b1  = (const float*)d_in[4];
    const float* w2  = (const float*)d_in[5];
    const float* b2  = (const float*)d_in[6];
    float* out = (float*)d_out;
    const int ntok = in_sizes[0] / H;      // 1048576, divisible by BT=128

    const int grid = ntok / BT;            // 8192 blocks of 128 threads
    ffn_kernel<<<grid, 128, 0, stream>>>(x, g, be, w1, b1, w2, b2, out, ntok);
}

// Round 11
// 126.605 us; speedup vs baseline: 1.0745x; 1.0745x over previous
//
#include <hip/hip_runtime.h>
#include <hip/hip_bf16.h>

// FFN: out = x + fc2(relu(fc1(LN(x)))), x:(ntok,16) fp32, ntok % 1024 == 0.
// R13: async-DMA staging (global_load_lds) + counted vmcnt — the T3/T4
// mechanism. R10/R11 proved register prefetch is compiler-defeated (loads
// sunk to use / pin costs scratch + drain). DMA staging holds NO VGPRs so it
// cannot be sunk; wave-private LDS slots need NO barriers; counted vmcnt(6)
// keeps 2 tiles + stores in flight across consumption (m218 evidence).
//  - per wave: 3 x 2KB LDS slots; iter it stages tile it+2, waits vmcnt
//    {4,6,...,6,4,2}, reads fragments AND residuals from LDS (x global-read
//    exactly once; residual global stream deleted).
//  - NIT=8, BT=1024, grid=1024 (4 blocks/CU, LDS 24KB/block).
//  - known cost: fragment LDS reads ~16-way bank conflict (~60ns/iter) --
//    accepted vs ~600ns latency recovered per iter.
// Carried: plain stores (R8), natural VGPR (R7), no reg pipelining (R10/R11).

constexpr int H     = 16;
constexpr int D     = 64;
constexpr int TPI   = 32;               // tokens per wave-iteration
constexpr int NIT   = 8;                // iterations per wave
constexpr int WAVES = 4;
constexpr int SLOTS = 3;                // LDS buffer slots (prefetch depth 2)
constexpr int BT    = WAVES * TPI * NIT;   // 1024 tokens per block

typedef __attribute__((ext_vector_type(8))) short    short8;
typedef __attribute__((ext_vector_type(4))) float    floatx4;
typedef __attribute__((ext_vector_type(4))) unsigned uintx4;

__device__ inline unsigned pk2(float a, float b) { // low = a, high = b
    __hip_bfloat162 h = __float22bfloat162_rn(make_float2(a, b));
    unsigned u; __builtin_memcpy(&u, &h, 4); return u;
}
__device__ inline floatx4 relu4(floatx4 v) {
    v.x = fmaxf(v.x, 0.f); v.y = fmaxf(v.y, 0.f);
    v.z = fmaxf(v.z, 0.f); v.w = fmaxf(v.w, 0.f);
    return v;
}

// fc1 (4 m-tiles) -> relu -> register repack -> fc2 (2 k-tiles), C-in = b2.
__device__ inline floatx4 tile_ffn(const short8* a1, const short8* a2,
                                   floatx4 c2, short8 by) {
    const floatx4 z = {0.f, 0.f, 0.f, 0.f};
    floatx4 h0 = relu4(__builtin_amdgcn_mfma_f32_16x16x32_bf16(a1[0], by, z, 0, 0, 0));
    floatx4 h1 = relu4(__builtin_amdgcn_mfma_f32_16x16x32_bf16(a1[1], by, z, 0, 0, 0));
    floatx4 h2 = relu4(__builtin_amdgcn_mfma_f32_16x16x32_bf16(a1[2], by, z, 0, 0, 0));
    floatx4 h3 = relu4(__builtin_amdgcn_mfma_f32_16x16x32_bf16(a1[3], by, z, 0, 0, 0));
    uintx4 r0 = { pk2(h0.x, h0.y), pk2(h0.z, h0.w), pk2(h1.x, h1.y), pk2(h1.z, h1.w) };
    uintx4 r1 = { pk2(h2.x, h2.y), pk2(h2.z, h2.w), pk2(h3.x, h3.y), pk2(h3.z, h3.w) };
    short8 bh0, bh1;
    __builtin_memcpy(&bh0, &r0, 16);
    __builtin_memcpy(&bh1, &r1, 16);
    floatx4 o = __builtin_amdgcn_mfma_f32_16x16x32_bf16(a2[0], bh0, c2, 0, 0, 0);
    o = __builtin_amdgcn_mfma_f32_16x16x32_bf16(a2[1], bh1, o, 0, 0, 0);
    return o;
}

__global__ __launch_bounds__(256, 4) void ffn_kernel(
    const float* __restrict__ x,
    const float* __restrict__ ln_g,
    const float* __restrict__ ln_b,
    const float* __restrict__ w1,
    const float* __restrict__ b1,
    const float* __restrict__ w2,
    const float* __restrict__ b2,
    float* __restrict__ out,
    int ntok)
{
    __shared__ float sx[WAVES][SLOTS][TPI * H];   // 4 x 3 x 2KB = 24KB

    const int tid = threadIdx.x;
    const int w = tid >> 6, l = tid & 63;
    const int li = l & 15, q = l >> 4;
    const int hb = q >> 1;           // 0: this lane's LN covers tile-A, 1: tile-B
    const int k0 = (q & 1) * 8;      // feature base this lane covers

    const int tok0 = blockIdx.x * BT + w * (TPI * NIT);

    // async DMA: 2 x 1KB per 32-token tile; LDS dest = uniform base + lane*16,
    // global src per-lane = lane-linear (tile stored token-major in LDS).
    #define STAGE(j_) do {                                                       \
        const int s_ = (j_) % SLOTS;                                             \
        const float* g_ = x + (size_t)(tok0 + (j_) * TPI) * H + 4 * l;           \
        __builtin_amdgcn_global_load_lds(                                        \
            (const __attribute__((address_space(1))) void*)(g_),                 \
            (__attribute__((address_space(3))) void*)&sx[w][s_][0], 16, 0, 0);   \
        __builtin_amdgcn_global_load_lds(                                        \
            (const __attribute__((address_space(1))) void*)(g_ + 256),           \
            (__attribute__((address_space(3))) void*)&sx[w][s_][256], 16, 0, 0); \
    } while (0)

    // prime: tiles 0 and 1 in flight before anything else
    STAGE(0);
    STAGE(1);

    // ---- per-lane weight fragments, direct from global (cache-resident) ----
    short8 a1[4];
    #pragma unroll
    for (int mt = 0; mt < 4; mt++) {
        const int d = 16 * mt + li;
        uintx4 u = {0u, 0u, 0u, 0u};
        if (q < 2) {
            floatx4 wa = *(const floatx4*)(w1 + d * H + k0);
            floatx4 wb = *(const floatx4*)(w1 + d * H + k0 + 4);
            u.x = pk2(wa.x, wa.y); u.y = pk2(wa.z, wa.w);
            u.z = pk2(wb.x, wb.y); u.w = pk2(wb.z, wb.w);
        } else if (q == 2) {
            u.x = pk2(b1[d], 0.f);   // k=16 slot carries b1 (B-side supplies 1.0)
        }
        __builtin_memcpy(&a1[mt], &u, 16);
    }
    short8 a2[2];
    #pragma unroll
    for (int kt = 0; kt < 2; kt++) {
        floatx4 wa = *(const floatx4*)(w2 + li * D + kt * 32 + 4 * q);
        floatx4 wb = *(const floatx4*)(w2 + li * D + kt * 32 + 16 + 4 * q);
        uintx4 u = { pk2(wa.x, wa.y), pk2(wa.z, wa.w), pk2(wb.x, wb.y), pk2(wb.z, wb.w) };
        __builtin_memcpy(&a2[kt], &u, 16);
    }
    const floatx4 c2 = *(const floatx4*)(b2 + 4 * q);
    const floatx4 ga = *(const floatx4*)(ln_g + k0);
    const floatx4 gb = *(const floatx4*)(ln_g + k0 + 4);
    const floatx4 ea = *(const floatx4*)(ln_b + k0);
    const floatx4 eb = *(const floatx4*)(ln_b + k0 + 4);

    #pragma unroll
    for (int it = 0; it < NIT; ++it) {
        if (it + 2 < NIT) STAGE(it + 2);

        // counted waits: tile `it` complete; tiles it+1/it+2 + newest stores
        // stay in flight. Outstanding budget (2 ops/tile, 2 stores/iter):
        //   it=0: allow {gl(1),gl(2)}           -> vmcnt(4)
        //   1..NIT-3: allow {gl(it+1),st(it-1),gl(it+2)} -> vmcnt(6)
        //   it=NIT-2: allow {gl(NIT-1),st(it-1)} -> vmcnt(4)
        //   it=NIT-1: allow {st(it-1)}           -> vmcnt(2)
        if (it == 0)            asm volatile("s_waitcnt vmcnt(4)" ::: "memory");
        else if (it < NIT - 2)  asm volatile("s_waitcnt vmcnt(6)" ::: "memory");
        else if (it == NIT - 2) asm volatile("s_waitcnt vmcnt(4)" ::: "memory");
        else                    asm volatile("s_waitcnt vmcnt(2)" ::: "memory");

        const float* tile = sx[w][it % SLOTS];
        // fragment: token tt = hb*16+li, features k0..k0+7
        const floatx4 xa = *(const floatx4*)&tile[(hb * 16 + li) * H + k0];
        const floatx4 xb = *(const floatx4*)&tile[(hb * 16 + li) * H + k0 + 4];
        // residuals (tile A: token li; tile B: token 16+li), floats 4q..4q+3
        const floatx4 xrA = *(const floatx4*)&tile[li * H + 4 * q];
        const floatx4 xrB = *(const floatx4*)&tile[(16 + li) * H + 4 * q];

        const int rA = (tok0 + it * TPI + li) * H + 4 * q;  // ntok*H < 2^31

        // ---- LN over this lane's 8 features (partner = lane^16) ----
        float ps = (xa.x + xa.y) + (xa.z + xa.w) + (xb.x + xb.y) + (xb.z + xb.w);
        float pq = 0.f;
        pq = fmaf(xa.x, xa.x, pq); pq = fmaf(xa.y, xa.y, pq);
        pq = fmaf(xa.z, xa.z, pq); pq = fmaf(xa.w, xa.w, pq);
        pq = fmaf(xb.x, xb.x, pq); pq = fmaf(xb.y, xb.y, pq);
        pq = fmaf(xb.z, xb.z, pq); pq = fmaf(xb.w, xb.w, pq);
        ps += __shfl_xor(ps, 16);
        pq += __shfl_xor(pq, 16);
        const float mean = ps * (1.0f / H);
        const float var  = fmaf(-mean, mean, pq * (1.0f / H));
        const float inv  = rsqrtf(var + 1e-5f);
        const float sa = inv, sb = -mean * inv;

        const float y0 = fmaf(fmaf(xa.x, sa, sb), ga.x, ea.x);
        const float y1 = fmaf(fmaf(xa.y, sa, sb), ga.y, ea.y);
        const float y2 = fmaf(fmaf(xa.z, sa, sb), ga.z, ea.z);
        const float y3 = fmaf(fmaf(xa.w, sa, sb), ga.w, ea.w);
        const float y4 = fmaf(fmaf(xb.x, sa, sb), gb.x, eb.x);
        const float y5 = fmaf(fmaf(xb.y, sa, sb), gb.y, eb.y);
        const float y6 = fmaf(fmaf(xb.z, sa, sb), gb.z, eb.z);
        const float y7 = fmaf(fmaf(xb.w, sa, sb), gb.w, eb.w);

        const unsigned p0 = pk2(y0, y1), p1 = pk2(y2, y3),
                       p2 = pk2(y4, y5), p3 = pk2(y6, y7);
        // hand tile-B's y (held by q>=2 lanes) to q<2 lanes, and vice versa
        const unsigned s0 = __shfl_xor(p0, 32), s1 = __shfl_xor(p1, 32),
                       s2 = __shfl_xor(p2, 32), s3 = __shfl_xor(p3, 32);

        const bool lo = (q < 2);
        const unsigned cq2 = (q == 2) ? 0x3F80u : 0u;  // bf16 1.0 at k=16 (b1 fold)
        uintx4 uA = { lo ? p0 : cq2, lo ? p1 : 0u, lo ? p2 : 0u, lo ? p3 : 0u };
        uintx4 uB = { lo ? s0 : cq2, lo ? s1 : 0u, lo ? s2 : 0u, lo ? s3 : 0u };
        short8 byA, byB;
        __builtin_memcpy(&byA, &uA, 16);
        __builtin_memcpy(&byB, &uB, 16);

        // ---- tile A: 16 tokens, residual + coalesced store ----
        floatx4 oA = tile_ffn(a1, a2, c2, byA);
        oA += xrA;
        *(floatx4*)(out + rA) = oA;
        // ---- tile B ----
        floatx4 oB = tile_ffn(a1, a2, c2, byB);
        oB += xrB;
        *(floatx4*)(out + rA + 16 * H) = oB;
    }
    #undef STAGE
    (void)ntok;
}

extern "C" void kernel_launch(void* const* d_in, const int* in_sizes, int n_in,
                              void* d_out, int out_size, void* d_ws, size_t ws_size,
                              hipStream_t stream) {
    const float* x   = (const float*)d_in[0];
    const float* g   = (const float*)d_in[1];
    const float* be  = (const float*)d_in[2];
    const float* w1  = (const float*)d_in[3];
    const float* b1  = (const float*)d_in[4];
    const float* w2  = (const float*)d_in[5];
    const float* b2  = (const float*)d_in[6];
    float* out = (float*)d_out;
    const int ntok = in_sizes[0] / H;      // 1048576, divisible by BT=1024

    const int grid = ntok / BT;            // 1024 blocks of 256 threads
    ffn_kernel<<<grid, 256, 0, stream>>>(x, g, be, w1, b1, w2, b2, out, ntok);
}

// Round 13
// 124.706 us; speedup vs baseline: 1.0909x; 1.0152x over previous
//
#include <hip/hip_runtime.h>
#include <hip/hip_bf16.h>

// FFN: out = x + fc2(relu(fc1(LN(x)))), x:(ntok,16) fp32, ntok % 1024 == 0.
// R15: R14 (depth-3 DMA staging) with the vmcnt race FIXED. R14 failed
// (absmax 1.3) because its wait counts assumed source order of the prologue:
// with no asm barriers, the scheduler can hoist the ~21 weight loads above
// the prologue STAGEs (and reorder the STAGEs), making wait(0)=vmcnt(4) and
// wait(2)=vmcnt(12) under-wait the tile's DMA. Fix:
//  - asm("" ::: "memory") after each prologue STAGE pins compile-time order
//    (no instruction emitted) so the count basis is guaranteed.
//  - waits derived from GUARANTEED-after ops only (stages+stores in
//    asm-delimited regions; weight loads ignored), minus margin 2:
//    {4,6,8,10,10,8,6,4}. Guaranteed-after: {6,8,10,12,12,10,8,6}.
// R13 (depth-2, margin>=2) passed and was the first real win (<40us);
// this tests whether depth 3 adds concurrency on top.
// Carried: plain stores (R8), natural VGPR (R7), no reg pipelining (R10/R11),
// residuals read from the staged LDS tile (x global-read exactly once).

constexpr int H     = 16;
constexpr int D     = 64;
constexpr int TPI   = 32;               // tokens per wave-iteration
constexpr int NIT   = 8;                // iterations per wave
constexpr int WAVES = 4;
constexpr int SLOTS = 4;                // LDS buffer slots (prefetch depth 3)
constexpr int BT    = WAVES * TPI * NIT;   // 1024 tokens per block

typedef __attribute__((ext_vector_type(8))) short    short8;
typedef __attribute__((ext_vector_type(4))) float    floatx4;
typedef __attribute__((ext_vector_type(4))) unsigned uintx4;

__device__ inline unsigned pk2(float a, float b) { // low = a, high = b
    __hip_bfloat162 h = __float22bfloat162_rn(make_float2(a, b));
    unsigned u; __builtin_memcpy(&u, &h, 4); return u;
}
__device__ inline floatx4 relu4(floatx4 v) {
    v.x = fmaxf(v.x, 0.f); v.y = fmaxf(v.y, 0.f);
    v.z = fmaxf(v.z, 0.f); v.w = fmaxf(v.w, 0.f);
    return v;
}

// fc1 (4 m-tiles) -> relu -> register repack -> fc2 (2 k-tiles), C-in = b2.
__device__ inline floatx4 tile_ffn(const short8* a1, const short8* a2,
                                   floatx4 c2, short8 by) {
    const floatx4 z = {0.f, 0.f, 0.f, 0.f};
    floatx4 h0 = relu4(__builtin_amdgcn_mfma_f32_16x16x32_bf16(a1[0], by, z, 0, 0, 0));
    floatx4 h1 = relu4(__builtin_amdgcn_mfma_f32_16x16x32_bf16(a1[1], by, z, 0, 0, 0));
    floatx4 h2 = relu4(__builtin_amdgcn_mfma_f32_16x16x32_bf16(a1[2], by, z, 0, 0, 0));
    floatx4 h3 = relu4(__builtin_amdgcn_mfma_f32_16x16x32_bf16(a1[3], by, z, 0, 0, 0));
    uintx4 r0 = { pk2(h0.x, h0.y), pk2(h0.z, h0.w), pk2(h1.x, h1.y), pk2(h1.z, h1.w) };
    uintx4 r1 = { pk2(h2.x, h2.y), pk2(h2.z, h2.w), pk2(h3.x, h3.y), pk2(h3.z, h3.w) };
    short8 bh0, bh1;
    __builtin_memcpy(&bh0, &r0, 16);
    __builtin_memcpy(&bh1, &r1, 16);
    floatx4 o = __builtin_amdgcn_mfma_f32_16x16x32_bf16(a2[0], bh0, c2, 0, 0, 0);
    o = __builtin_amdgcn_mfma_f32_16x16x32_bf16(a2[1], bh1, o, 0, 0, 0);
    return o;
}

__global__ __launch_bounds__(256, 4) void ffn_kernel(
    const float* __restrict__ x,
    const float* __restrict__ ln_g,
    const float* __restrict__ ln_b,
    const float* __restrict__ w1,
    const float* __restrict__ b1,
    const float* __restrict__ w2,
    const float* __restrict__ b2,
    float* __restrict__ out,
    int ntok)
{
    __shared__ float sx[WAVES][SLOTS][TPI * H];   // 4 x 4 x 2KB = 32KB

    const int tid = threadIdx.x;
    const int w = tid >> 6, l = tid & 63;
    const int li = l & 15, q = l >> 4;
    const int hb = q >> 1;           // 0: this lane's LN covers tile-A, 1: tile-B
    const int k0 = (q & 1) * 8;      // feature base this lane covers

    const int tok0 = blockIdx.x * BT + w * (TPI * NIT);

    // async DMA: 2 x 1KB per 32-token tile; LDS dest = uniform base + lane*16,
    // global src per-lane = lane-linear (tile stored token-major in LDS).
    #define STAGE(j_) do {                                                       \
        const int s_ = (j_) % SLOTS;                                             \
        const float* g_ = x + (size_t)(tok0 + (j_) * TPI) * H + 4 * l;           \
        __builtin_amdgcn_global_load_lds(                                        \
            (const __attribute__((address_space(1))) void*)(g_),                 \
            (__attribute__((address_space(3))) void*)&sx[w][s_][0], 16, 0, 0);   \
        __builtin_amdgcn_global_load_lds(                                        \
            (const __attribute__((address_space(1))) void*)(g_ + 256),           \
            (__attribute__((address_space(3))) void*)&sx[w][s_][256], 16, 0, 0); \
    } while (0)

    // prime: tiles 0..2 in flight, ORDER PINNED (compile-time barriers so the
    // vmcnt count basis below is guaranteed; weights cannot hoist above these)
    STAGE(0);
    asm volatile("" ::: "memory");
    STAGE(1);
    asm volatile("" ::: "memory");
    STAGE(2);
    asm volatile("" ::: "memory");

    // ---- per-lane weight fragments, direct from global (cache-resident) ----
    short8 a1[4];
    #pragma unroll
    for (int mt = 0; mt < 4; mt++) {
        const int d = 16 * mt + li;
        uintx4 u = {0u, 0u, 0u, 0u};
        if (q < 2) {
            floatx4 wa = *(const floatx4*)(w1 + d * H + k0);
            floatx4 wb = *(const floatx4*)(w1 + d * H + k0 + 4);
            u.x = pk2(wa.x, wa.y); u.y = pk2(wa.z, wa.w);
            u.z = pk2(wb.x, wb.y); u.w = pk2(wb.z, wb.w);
        } else if (q == 2) {
            u.x = pk2(b1[d], 0.f);   // k=16 slot carries b1 (B-side supplies 1.0)
        }
        __builtin_memcpy(&a1[mt], &u, 16);
    }
    short8 a2[2];
    #pragma unroll
    for (int kt = 0; kt < 2; kt++) {
        floatx4 wa = *(const floatx4*)(w2 + li * D + kt * 32 + 4 * q);
        floatx4 wb = *(const floatx4*)(w2 + li * D + kt * 32 + 16 + 4 * q);
        uintx4 u = { pk2(wa.x, wa.y), pk2(wa.z, wa.w), pk2(wb.x, wb.y), pk2(wb.z, wb.w) };
        __builtin_memcpy(&a2[kt], &u, 16);
    }
    const floatx4 c2 = *(const floatx4*)(b2 + 4 * q);
    const floatx4 ga = *(const floatx4*)(ln_g + k0);
    const floatx4 gb = *(const floatx4*)(ln_g + k0 + 4);
    const floatx4 ea = *(const floatx4*)(ln_b + k0);
    const floatx4 eb = *(const floatx4*)(ln_b + k0 + 4);

    #pragma unroll
    for (int it = 0; it < NIT; ++it) {
        if (it + 3 < NIT) STAGE(it + 3);

        // Waits derived from GUARANTEED-after-STAGE(it) VMEM ops (stages and
        // stores inside asm-delimited regions; weight loads not counted since
        // their placement is scheduler-chosen), minus margin 2:
        //   it=0: guaranteed {S1,S2,S3}=6            -> vmcnt(4)
        //   it=1: {S2,S3,st0,S4}=8                   -> vmcnt(6)
        //   it=2: {S3,st0,S4,st1,S5}=10              -> vmcnt(8)
        //   steady: {st,S,st,S,st,S}=12              -> vmcnt(10)
        //   it=NIT-3: 10 -> 8; NIT-2: 8 -> 6; NIT-1: 6 -> 4
        if (it == 0)            asm volatile("s_waitcnt vmcnt(4)"  ::: "memory");
        else if (it == 1)       asm volatile("s_waitcnt vmcnt(6)"  ::: "memory");
        else if (it == 2)       asm volatile("s_waitcnt vmcnt(8)"  ::: "memory");
        else if (it < NIT - 3)  asm volatile("s_waitcnt vmcnt(10)" ::: "memory");
        else if (it == NIT - 3) asm volatile("s_waitcnt vmcnt(8)"  ::: "memory");
        else if (it == NIT - 2) asm volatile("s_waitcnt vmcnt(6)"  ::: "memory");
        else                    asm volatile("s_waitcnt vmcnt(4)"  ::: "memory");

        const float* tile = sx[w][it % SLOTS];
        // fragment: token tt = hb*16+li, features k0..k0+7
        const floatx4 xa = *(const floatx4*)&tile[(hb * 16 + li) * H + k0];
        const floatx4 xb = *(const floatx4*)&tile[(hb * 16 + li) * H + k0 + 4];
        // residuals (tile A: token li; tile B: token 16+li), floats 4q..4q+3
        const floatx4 xrA = *(const floatx4*)&tile[li * H + 4 * q];
        const floatx4 xrB = *(const floatx4*)&tile[(16 + li) * H + 4 * q];

        const int rA = (tok0 + it * TPI + li) * H + 4 * q;  // ntok*H < 2^31

        // ---- LN over this lane's 8 features (partner = lane^16) ----
        float ps = (xa.x + xa.y) + (xa.z + xa.w) + (xb.x + xb.y) + (xb.z + xb.w);
        float pq = 0.f;
        pq = fmaf(xa.x, xa.x, pq); pq = fmaf(xa.y, xa.y, pq);
        pq = fmaf(xa.z, xa.z, pq); pq = fmaf(xa.w, xa.w, pq);
        pq = fmaf(xb.x, xb.x, pq); pq = fmaf(xb.y, xb.y, pq);
        pq = fmaf(xb.z, xb.z, pq); pq = fmaf(xb.w, xb.w, pq);
        ps += __shfl_xor(ps, 16);
        pq += __shfl_xor(pq, 16);
        const float mean = ps * (1.0f / H);
        const float var  = fmaf(-mean, mean, pq * (1.0f / H));
        const float inv  = rsqrtf(var + 1e-5f);
        const float sa = inv, sb = -mean * inv;

        const float y0 = fmaf(fmaf(xa.x, sa, sb), ga.x, ea.x);
        const float y1 = fmaf(fmaf(xa.y, sa, sb), ga.y, ea.y);
        const float y2 = fmaf(fmaf(xa.z, sa, sb), ga.z, ea.z);
        const float y3 = fmaf(fmaf(xa.w, sa, sb), ga.w, ea.w);
        const float y4 = fmaf(fmaf(xb.x, sa, sb), gb.x, eb.x);
        const float y5 = fmaf(fmaf(xb.y, sa, sb), gb.y, eb.y);
        const float y6 = fmaf(fmaf(xb.z, sa, sb), gb.z, eb.z);
        const float y7 = fmaf(fmaf(xb.w, sa, sb), gb.w, eb.w);

        const unsigned p0 = pk2(y0, y1), p1 = pk2(y2, y3),
                       p2 = pk2(y4, y5), p3 = pk2(y6, y7);
        // hand tile-B's y (held by q>=2 lanes) to q<2 lanes, and vice versa
        const unsigned s0 = __shfl_xor(p0, 32), s1 = __shfl_xor(p1, 32),
                       s2 = __shfl_xor(p2, 32), s3 = __shfl_xor(p3, 32);

        const bool lo = (q < 2);
        const unsigned cq2 = (q == 2) ? 0x3F80u : 0u;  // bf16 1.0 at k=16 (b1 fold)
        uintx4 uA = { lo ? p0 : cq2, lo ? p1 : 0u, lo ? p2 : 0u, lo ? p3 : 0u };
        uintx4 uB = { lo ? s0 : cq2, lo ? s1 : 0u, lo ? s2 : 0u, lo ? s3 : 0u };
        short8 byA, byB;
        __builtin_memcpy(&byA, &uA, 16);
        __builtin_memcpy(&byB, &uB, 16);

        // ---- tile A: 16 tokens, residual + coalesced store ----
        floatx4 oA = tile_ffn(a1, a2, c2, byA);
        oA += xrA;
        *(floatx4*)(out + rA) = oA;
        // ---- tile B ----
        floatx4 oB = tile_ffn(a1, a2, c2, byB);
        oB += xrB;
        *(floatx4*)(out + rA + 16 * H) = oB;
    }
    #undef STAGE
    (void)ntok;
}

extern "C" void kernel_launch(void* const* d_in, const int* in_sizes, int n_in,
                              void* d_out, int out_size, void* d_ws, size_t ws_size,
                              hipStream_t stream) {
    const float* x   = (const float*)d_in[0];
    const float* g   = (const float*)d_in[1];
    const float* be  = (const float*)d_in[2];
    const float* w1  = (const float*)d_in[3];
    const float* b1  = (const float*)d_in[4];
    const float* w2  = (const float*)d_in[5];
    const float* b2  = (const float*)d_in[6];
    float* out = (float*)d_out;
    const int ntok = in_sizes[0] / H;      // 1048576, divisible by BT=1024

    const int grid = ntok / BT;            // 1024 blocks of 256 threads
    ffn_kernel<<<grid, 256, 0, stream>>>(x, g, be, w1, b1, w2, b2, out, ntok);
}